// Round 5
// baseline (170.584 us; speedup 1.0000x reference)
//
#include <hip/hip_runtime.h>

// Problem constants: x [B=1,T=8,C=32,D=32,H=64,W=64] fp32
constexpr int NT = 8;    // B*T
constexpr int C  = 32;
constexpr int D  = 32;
constexpr int H  = 64;
constexpr int W  = 64;   // == wavefront size: W-conv via lane shuffles
constexpr int SP = D * H * W;       // per-channel spatial size = 131072
constexpr int HW = H * W;           // d-plane stride = 4096

// ---------------------------------------------------------------------------
// Fully fused LSKA block, ZERO LDS. Block = (n, hg) row, 512 threads = 8 waves.
//
// Phase A (depthwise chain, round-4 proven code): wave r computes channels
//   {r, r+8, r+16, r+24} sequentially; lane = w; thread owns the full D=32
//   column in registers. h written to d_out (h-buffer role).
// __syncthreads()  — every h value phase B needs was written by THIS block.
// Phase B (pointwise + residual, round-2/4 proven pw_mul pattern): thread
//   (dq = tid>>6, w) handles d in {dq, dq+8, dq+16, dq+24}: reads all 32
//   channels of h (own block's writes, L1/L2-hot), 32x32 mix in fp32,
//   multiplies by x (lines fetched by phase A => L2-hot), writes out in
//   place. Per-thread read-all-then-write-all => in-place safe.
//
// No LDS => residency capped only by VGPRs; launch_bounds(512,6) targets
// 24 waves/CU (3 blocks), ~2x round-4 occupancy, to hide memory latency.
// Boundary bias semantics: a later conv's out-of-image tap drops its whole
// term (incl. earlier biases) — implemented as clamped row address + zeroed
// tap weight (term enters as wxk*(zconv+bz), so wxk=0 is exact).
// ---------------------------------------------------------------------------
__global__ __launch_bounds__(512, 6)
void lska_fused(const float* __restrict__ x,
                const float* __restrict__ w0z, const float* __restrict__ b0z,
                const float* __restrict__ w0x, const float* __restrict__ b0x,
                const float* __restrict__ w0y, const float* __restrict__ b0y,
                const float* __restrict__ wsz, const float* __restrict__ bsz,
                const float* __restrict__ wp,  const float* __restrict__ bp,
                float* __restrict__ out)
{
    // XCD-chunk swizzle: 512 blocks, 8 XCDs, chunk 64 => XCD k owns n = k
    // entirely (all hg consecutive): halo-row and residual re-reads stay in
    // that XCD's L2.
    const int rr  = blockIdx.x;
    const int lid = (rr & 7) * (NT * H / 8) + (rr >> 3);
    const int n   = lid >> 6;            // 0..7
    const int hg  = lid & 63;            // 0..63

    const int tid = threadIdx.x;
    const int w   = tid & 63;            // lane
    const int r   = tid >> 6;            // wave 0..7

    // ---------------- Phase A: depthwise chain, 4 channels per wave --------
    #pragma unroll 1
    for (int cc = 0; cc < 4; ++cc) {
        const int c = r + cc * 8;        // wave-uniform
        const float* xc = x + ((size_t)n * C + c) * SP;

        const float wz0 = w0z[c*3+0], wz1 = w0z[c*3+1], wz2 = w0z[c*3+2];
        const float wx1 = w0x[c*3+1];
        const float wy0 = w0y[c*3+0], wy1 = w0y[c*3+1], wy2 = w0y[c*3+2];
        const float bz = b0z[c], bx = b0x[c], by = b0y[c], bs = bsz[c];
        float wsk[5];
        #pragma unroll
        for (int k = 0; k < 5; ++k) wsk[k] = wsz[c*5+k];

        // Boundary: clamp row index (legal load), zero the tap weight (exact).
        const float wxk0 = (hg > 0)     ? w0x[c*3+0] : 0.f;
        const float wxk2 = (hg < H - 1) ? w0x[c*3+2] : 0.f;
        const int   hm = (hg > 0)     ? hg - 1 : 0;
        const int   hp = (hg < H - 1) ? hg + 1 : H - 1;

        const float* p0 = xc + (size_t)hm * W + w;
        const float* p1 = xc + (size_t)hg * W + w;
        const float* p2 = xc + (size_t)hp * W + w;

        // h-conv (along H) immediately per d: hrow = wxk0*r0 + wx1*r1 + wxk2*r2
        float hrow[D];
        #pragma unroll
        for (int d = 0; d < D; ++d) {
            float a0 = p0[(size_t)d * HW];
            float a1 = p1[(size_t)d * HW];
            float a2 = p2[(size_t)d * HW];
            hrow[d] = wxk0 * a0 + wx1 * a1 + wxk2 * a2;
        }

        // z-conv (along D) + folded biases
        const float cb = bx + (wxk0 + wx1 + wxk2) * bz;
        float acc2[D];
        #pragma unroll
        for (int d = 0; d < D; ++d) {
            float t = cb + wz1 * hrow[d];
            if (d > 0)     t += wz0 * hrow[d - 1];
            if (d < D - 1) t += wz2 * hrow[d + 1];
            acc2[d] = t;
        }

        // w-conv via lane shuffles (W == 64 == wavefront)
        const bool has_l = (w > 0), has_r = (w < W - 1);
        float acc3[D];
        #pragma unroll
        for (int d = 0; d < D; ++d) {
            float left  = __shfl_up(acc2[d], 1);
            float right = __shfl_down(acc2[d], 1);
            float t = by + wy1 * acc2[d];
            if (has_l) t += wy0 * left;
            if (has_r) t += wy2 * right;
            acc3[d] = t;
        }

        // three 5-tap dilation-2 convs along D (pad 4), in registers
        #pragma unroll
        for (int it = 0; it < 3; ++it) {
            float s[D];
            #pragma unroll
            for (int d = 0; d < D; ++d) {
                float t = bs;
                #pragma unroll
                for (int k = 0; k < 5; ++k) {
                    int j = d + 2 * k - 4;
                    if (j >= 0 && j < D) t += wsk[k] * acc3[j];
                }
                s[d] = t;
            }
            #pragma unroll
            for (int d = 0; d < D; ++d) acc3[d] = s[d];
        }

        // store h column into out (h-buffer role), coalesced across lanes
        float* oc = out + ((size_t)n * C + c) * SP + (size_t)hg * W + w;
        #pragma unroll
        for (int d = 0; d < D; ++d) oc[(size_t)d * HW] = acc3[d];
    }

    __syncthreads();   // all h values for this (n, hg) row now visible in-block

    // ---------------- Phase B: pointwise mix + residual, in place ----------
    const int dq = tid >> 6;             // 0..7
    #pragma unroll 1
    for (int k = 0; k < 4; ++k) {
        const int d = dq + k * 8;
        const size_t base = (size_t)n * C * SP + (size_t)d * HW
                          + (size_t)hg * W + w;

        float v[C];
        #pragma unroll
        for (int ci = 0; ci < C; ++ci) v[ci] = out[base + (size_t)ci * SP];

        for (int co = 0; co < C; ++co) {
            float y = bp[co];
            #pragma unroll
            for (int ci = 0; ci < C; ++ci) y += wp[co * C + ci] * v[ci];
            const size_t idx = base + (size_t)co * SP;
            out[idx] = x[idx] * y;
        }
    }
}

extern "C" void kernel_launch(void* const* d_in, const int* in_sizes, int n_in,
                              void* d_out, int out_size, void* d_ws, size_t ws_size,
                              hipStream_t stream)
{
    const float* x   = (const float*)d_in[0];
    const float* w0z = (const float*)d_in[1];
    const float* b0z = (const float*)d_in[2];
    const float* w0x = (const float*)d_in[3];
    const float* b0x = (const float*)d_in[4];
    const float* w0y = (const float*)d_in[5];
    const float* b0y = (const float*)d_in[6];
    const float* wsz = (const float*)d_in[7];
    const float* bsz = (const float*)d_in[8];
    const float* wp  = (const float*)d_in[9];
    const float* bp  = (const float*)d_in[10];
    float* out = (float*)d_out;

    const int grid = NT * H;             // 512 blocks, 512 threads each
    lska_fused<<<grid, 512, 0, stream>>>(
        x, w0z, b0z, w0x, b0x, w0y, b0y, wsz, bsz, wp, bp, out);
}

// Round 6
// 112.044 us; speedup vs baseline: 1.5225x; 1.5225x over previous
//
#include <hip/hip_runtime.h>

// Problem constants: x [B=1,T=8,C=32,D=32,H=64,W=64] fp32
constexpr int NT = 8;    // B*T
constexpr int C  = 32;
constexpr int D  = 32;
constexpr int H  = 64;
constexpr int W  = 64;   // == wavefront size: W-conv via lane shuffles
constexpr int ROWS = 4;  // h rows per block (one per wave)
constexpr int SP = D * H * W;       // per-channel spatial size = 131072
constexpr int HW = H * W;           // d-plane stride = 4096

// ---------------------------------------------------------------------------
// Kernel A: fused depthwise chain, LDS-free.
//   h = zconv3(x)+bz ; h = hconv3(h)+bx ; h = wconv3(h)+by ; 3x: h = zconv5_dil2(h)+bs
// One wave per (n,c,h) row; lane = w; thread owns the full D=32 column in regs.
//
// Round-6 latency fixes:
//  * hg forced scalar via readfirstlane -> all load/store base addresses are
//    SALU (uniform base + w*4 vector offset); no v_add_co/vcc chains.
//  * all 96 loads pinned live in VGPRs by a volatile asm fence -> 96 loads
//    in flight per wave instead of ~8-24 (compiler can no longer sink them).
//  * launch_bounds(256,4): VGPR cap 128 (96 pinned + overhead fits).
//
// Boundary bias semantics: a later conv's out-of-image tap drops its whole
// term (incl. earlier biases) — clamped row address + zeroed tap weight
// (term enters as wxk*(zconv+bz), so wxk=0 is exact).
// ---------------------------------------------------------------------------
__global__ __launch_bounds__(256, 4)
void dw_chain(const float* __restrict__ x,
              const float* __restrict__ w0z, const float* __restrict__ b0z,
              const float* __restrict__ w0x, const float* __restrict__ b0x,
              const float* __restrict__ w0y, const float* __restrict__ b0y,
              const float* __restrict__ wsz, const float* __restrict__ bsz,
              float* __restrict__ hdw)
{
    // XCD-chunk swizzle: 4096 blocks, 8 XCDs, chunk = 512 => XCD k owns one n
    // entirely: halo-row re-reads stay in that XCD's L2.
    const int rr  = blockIdx.x;
    const int lid = (rr & 7) * (NT * C * (H / ROWS) / 8) + (rr >> 3);
    const int htile = lid % (H / ROWS);
    const int c     = (lid / (H / ROWS)) % C;
    const int n     = lid / ((H / ROWS) * C);

    const int tid = threadIdx.x;
    const int w   = tid & 63;                              // lane (divergent)
    // wave-uniform h row, forced into an SGPR:
    const int hg  = __builtin_amdgcn_readfirstlane(htile * ROWS + (tid >> 6));

    const float* xc = x + ((size_t)n * C + c) * SP;

    // Per-channel weights (block-uniform -> scalar regs)
    const float wz0 = w0z[c*3+0], wz1 = w0z[c*3+1], wz2 = w0z[c*3+2];
    const float wx1 = w0x[c*3+1];
    const float wy0 = w0y[c*3+0], wy1 = w0y[c*3+1], wy2 = w0y[c*3+2];
    const float bz = b0z[c], bx = b0x[c], by = b0y[c], bs = bsz[c];
    float wsk[5];
    #pragma unroll
    for (int k = 0; k < 5; ++k) wsk[k] = wsz[c*5+k];

    // Boundary: clamp row index (legal load), zero the tap weight (exact).
    const float wxk0 = (hg > 0)     ? w0x[c*3+0] : 0.f;
    const float wxk2 = (hg < H - 1) ? w0x[c*3+2] : 0.f;
    const int   hm = (hg > 0)     ? hg - 1 : 0;
    const int   hp = (hg < H - 1) ? hg + 1 : H - 1;

    // Scalar row base pointers (SGPR); only +w is vector.
    const float* p0 = xc + (size_t)hm * W;
    const float* p1 = xc + (size_t)hg * W;
    const float* p2 = xc + (size_t)hp * W;

    // ---- Issue ALL 96 loads; pin results live in VGPRs ------------------
    float a0[D], a1[D], a2[D];
    #pragma unroll
    for (int d = 0; d < D; ++d) {
        a0[d] = p0[(size_t)d * HW + w];
        a1[d] = p1[(size_t)d * HW + w];
        a2[d] = p2[(size_t)d * HW + w];
    }
    #pragma unroll
    for (int d = 0; d < D; ++d)
        asm volatile("" : "+v"(a0[d]), "+v"(a1[d]), "+v"(a2[d]));

    // ---- h-conv (along H): hrow = wxk0*r0 + wx1*r1 + wxk2*r2 ------------
    float hrow[D];
    #pragma unroll
    for (int d = 0; d < D; ++d)
        hrow[d] = wxk0 * a0[d] + wx1 * a1[d] + wxk2 * a2[d];

    // ---- z-conv (along D) + folded biases --------------------------------
    const float cb = bx + (wxk0 + wx1 + wxk2) * bz;
    float acc2[D];
    #pragma unroll
    for (int d = 0; d < D; ++d) {
        float t = cb + wz1 * hrow[d];
        if (d > 0)     t += wz0 * hrow[d - 1];
        if (d < D - 1) t += wz2 * hrow[d + 1];
        acc2[d] = t;
    }

    // ---- w-conv via lane shuffles (W == 64 == wavefront) -----------------
    const bool has_l = (w > 0), has_r = (w < W - 1);
    float acc3[D];
    #pragma unroll
    for (int d = 0; d < D; ++d) {
        float left  = __shfl_up(acc2[d], 1);
        float right = __shfl_down(acc2[d], 1);
        float t = by + wy1 * acc2[d];
        if (has_l) t += wy0 * left;
        if (has_r) t += wy2 * right;
        acc3[d] = t;
    }

    // ---- three 5-tap dilation-2 convs along D (pad 4), in registers ------
    #pragma unroll
    for (int it = 0; it < 3; ++it) {
        float s[D];
        #pragma unroll
        for (int d = 0; d < D; ++d) {
            float t = bs;
            #pragma unroll
            for (int k = 0; k < 5; ++k) {
                int j = d + 2 * k - 4;
                if (j >= 0 && j < D) t += wsk[k] * acc3[j];
            }
            s[d] = t;
        }
        #pragma unroll
        for (int d = 0; d < D; ++d) acc3[d] = s[d];
    }

    // ---- store column: scalar base + w (coalesced across lanes) ----------
    float* oc = hdw + ((size_t)n * C + c) * SP + (size_t)hg * W;
    #pragma unroll
    for (int d = 0; d < D; ++d) oc[(size_t)d * HW + w] = acc3[d];
}

// ---------------------------------------------------------------------------
// Kernel B: pointwise 1x1x1 conv over channels + residual multiply, IN PLACE
// on io (= d_out holding the depthwise-chain result). Near mixed L3/HBM
// roofline — unchanged from round 4.
// ---------------------------------------------------------------------------
__global__ __launch_bounds__(256)
void pw_mul(const float* __restrict__ x,
            const float* __restrict__ wp, const float* __restrict__ bp,
            float* __restrict__ io)
{
    const size_t p = (size_t)blockIdx.x * 256 + threadIdx.x;  // (n, d, h, w)
    const size_t n  = p / SP;
    const size_t sp = p % SP;
    const size_t base = n * (size_t)C * SP + sp;

    float v[C];
    #pragma unroll
    for (int ci = 0; ci < C; ++ci) v[ci] = io[base + (size_t)ci * SP];

    for (int co = 0; co < C; ++co) {
        float y = bp[co];
        #pragma unroll
        for (int ci = 0; ci < C; ++ci) y += wp[co * C + ci] * v[ci];
        const size_t idx = base + (size_t)co * SP;
        io[idx] = x[idx] * y;
    }
}

extern "C" void kernel_launch(void* const* d_in, const int* in_sizes, int n_in,
                              void* d_out, int out_size, void* d_ws, size_t ws_size,
                              hipStream_t stream)
{
    const float* x   = (const float*)d_in[0];
    const float* w0z = (const float*)d_in[1];
    const float* b0z = (const float*)d_in[2];
    const float* w0x = (const float*)d_in[3];
    const float* b0x = (const float*)d_in[4];
    const float* w0y = (const float*)d_in[5];
    const float* b0y = (const float*)d_in[6];
    const float* wsz = (const float*)d_in[7];
    const float* bsz = (const float*)d_in[8];
    const float* wp  = (const float*)d_in[9];
    const float* bp  = (const float*)d_in[10];
    float* out = (float*)d_out;

    // Kernel A: depthwise chain -> d_out (scratch)
    const int gridA = NT * C * (H / ROWS);        // 4096 blocks, 256 thr
    dw_chain<<<gridA, 256, 0, stream>>>(x, w0z, b0z, w0x, b0x, w0y, b0y,
                                        wsz, bsz, out);

    // Kernel B: pointwise + residual, in place on d_out
    const int positions = NT * SP;                // 1,048,576
    pw_mul<<<positions / 256, 256, 0, stream>>>(x, wp, bp, out);
}